// Round 1
// baseline (8048.076 us; speedup 1.0000x reference)
//
#include <hip/hip_runtime.h>
#include <hip/hip_bf16.h>

// ---------------------------------------------------------------------------
// GCN forward: 4 x (GEMM + sym-norm sparse aggregation) with ReLU / softmax.
// Round 1: all-f32, atomics-based scatter. Structure:
//   deg -> dinv (per call, tiny)
//   per layer: k_gemm (writes Lin AND Agg-init = Lin*dinv[m]^2, i.e. self-loop)
//              k_edge (atomic scatter-add of Lin[src]*dinv[s]*dinv[d] into Agg[dst])
//              k_bias_relu (layers 1-3) | k_softmax_bias (layer 4, in-place d_out)
// ---------------------------------------------------------------------------

#define THREADS 256

__global__ void k_fill1(float* __restrict__ p, int n) {
    int i = blockIdx.x * blockDim.x + threadIdx.x;
    if (i < n) p[i] = 1.0f;
}

__global__ void k_deg(const int* __restrict__ dst, float* __restrict__ deg, int E, int n) {
    int i = blockIdx.x * blockDim.x + threadIdx.x;
    if (i < E) {
        int d = dst[i];
        if (d >= 0 && d < n) unsafeAtomicAdd(&deg[d], 1.0f);
    }
}

__global__ void k_dinv(float* __restrict__ p, int n) {
    int i = blockIdx.x * blockDim.x + threadIdx.x;
    if (i < n) p[i] = 1.0f / sqrtf(p[i]);   // deg >= 1 always (self-loop)
}

// C = A(MxK) @ W(NxK)^T.  Lin = C ; Agg = C * dinv[m]^2  (self-loop init).
// BM=BN=64, BK=32, 256 threads, 4x4 per thread.
__global__ __launch_bounds__(256) void k_gemm(
    const float* __restrict__ A, const float* __restrict__ W,
    float* __restrict__ Lin, float* __restrict__ Agg,
    const float* __restrict__ dinv, int M, int N, int K)
{
    __shared__ float As[32][68];   // [k][m], pad 68 -> float4-aligned columns
    __shared__ float Bs[32][68];   // [k][n]

    const int tid = threadIdx.x;
    const int m0 = blockIdx.x * 64;
    const int n0 = blockIdx.y * 64;
    const int tx = tid & 15;       // -> 4 cols
    const int ty = tid >> 4;       // -> 4 rows

    float acc[4][4] = {};

    for (int k0 = 0; k0 < K; k0 += 32) {
#pragma unroll
        for (int l = 0; l < 2; ++l) {
            int f   = tid + l * 256;      // 0..511 float4 slots
            int row = f >> 3;             // 0..63
            int c4  = f & 7;              // 0..7 (float4 col)
            int m   = m0 + row;
            float4 v = make_float4(0.f, 0.f, 0.f, 0.f);
            if (m < M) v = *(const float4*)(A + (size_t)m * K + k0 + c4 * 4);
            As[c4 * 4 + 0][row] = v.x;
            As[c4 * 4 + 1][row] = v.y;
            As[c4 * 4 + 2][row] = v.z;
            As[c4 * 4 + 3][row] = v.w;
            // N is a multiple of 64 -> no guard
            float4 w = *(const float4*)(W + (size_t)(n0 + row) * K + k0 + c4 * 4);
            Bs[c4 * 4 + 0][row] = w.x;
            Bs[c4 * 4 + 1][row] = w.y;
            Bs[c4 * 4 + 2][row] = w.z;
            Bs[c4 * 4 + 3][row] = w.w;
        }
        __syncthreads();

#pragma unroll
        for (int k = 0; k < 32; ++k) {
            float a[4], b[4];
#pragma unroll
            for (int i = 0; i < 4; ++i) a[i] = As[k][ty * 4 + i];
#pragma unroll
            for (int j = 0; j < 4; ++j) b[j] = Bs[k][tx * 4 + j];
#pragma unroll
            for (int i = 0; i < 4; ++i)
#pragma unroll
                for (int j = 0; j < 4; ++j) acc[i][j] += a[i] * b[j];
        }
        __syncthreads();
    }

#pragma unroll
    for (int i = 0; i < 4; ++i) {
        int m = m0 + ty * 4 + i;
        if (m >= M) break;
        float s = dinv[m]; s = s * s;
        float4 c = make_float4(acc[i][0], acc[i][1], acc[i][2], acc[i][3]);
        *(float4*)(Lin + (size_t)m * N + n0 + tx * 4) = c;
        float4 g = make_float4(c.x * s, c.y * s, c.z * s, c.w * s);
        *(float4*)(Agg + (size_t)m * N + n0 + tx * 4) = g;
    }
}

// Scatter: Agg[dst] += Lin[src] * dinv[src]*dinv[dst], float4 per thread.
__global__ void k_edge(const float* __restrict__ Lin, float* __restrict__ Agg,
                       const int* __restrict__ src, const int* __restrict__ dst,
                       const float* __restrict__ dinv, int E, int D, int logPer, int n)
{
    const int per = 1 << logPer;                 // D/4
    const long long total  = (long long)E << logPer;
    const long long stride = (long long)gridDim.x * blockDim.x;
    for (long long i = (long long)blockIdx.x * blockDim.x + threadIdx.x;
         i < total; i += stride) {
        const int e = (int)(i >> logPer);
        const int c = ((int)i & (per - 1)) << 2;
        const int s = src[e];
        const int d = dst[e];
        if ((unsigned)s >= (unsigned)n || (unsigned)d >= (unsigned)n) continue; // crash guard
        const float w  = dinv[s] * dinv[d];
        const float4 v = *(const float4*)(Lin + (size_t)s * D + c);
        float* p = Agg + (size_t)d * D + c;
        unsafeAtomicAdd(p + 0, v.x * w);
        unsafeAtomicAdd(p + 1, v.y * w);
        unsafeAtomicAdd(p + 2, v.z * w);
        unsafeAtomicAdd(p + 3, v.w * w);
    }
}

__global__ void k_bias_relu(float* __restrict__ H, const float* __restrict__ bias,
                            long long total4, int maskPer4)
{
    const long long stride = (long long)gridDim.x * blockDim.x;
    for (long long i = (long long)blockIdx.x * blockDim.x + threadIdx.x;
         i < total4; i += stride) {
        int c = ((int)i & maskPer4) << 2;
        float4 v = *(float4*)(H + (i << 2));
        float4 b = *(const float4*)(bias + c);
        v.x = fmaxf(v.x + b.x, 0.f);
        v.y = fmaxf(v.y + b.y, 0.f);
        v.z = fmaxf(v.z + b.z, 0.f);
        v.w = fmaxf(v.w + b.w, 0.f);
        *(float4*)(H + (i << 2)) = v;
    }
}

// In-place softmax over rows of 256 (+ bias). One wave (64 lanes) per row.
__global__ __launch_bounds__(256) void k_softmax_bias(float* __restrict__ IO,
                                                      const float* __restrict__ bias, int M)
{
    int row  = blockIdx.x * 4 + (threadIdx.x >> 6);
    int lane = threadIdx.x & 63;
    if (row >= M) return;
    float* p = IO + (size_t)row * 256 + lane * 4;
    float4 v = *(float4*)p;
    const float4 b = *(const float4*)(bias + lane * 4);
    v.x += b.x; v.y += b.y; v.z += b.z; v.w += b.w;
    float m = fmaxf(fmaxf(v.x, v.y), fmaxf(v.z, v.w));
#pragma unroll
    for (int off = 32; off > 0; off >>= 1) m = fmaxf(m, __shfl_xor(m, off));
    float e0 = expf(v.x - m), e1 = expf(v.y - m), e2 = expf(v.z - m), e3 = expf(v.w - m);
    float s = e0 + e1 + e2 + e3;
#pragma unroll
    for (int off = 32; off > 0; off >>= 1) s += __shfl_xor(s, off);
    float inv = 1.0f / s;
    v.x = e0 * inv; v.y = e1 * inv; v.z = e2 * inv; v.w = e3 * inv;
    *(float4*)p = v;
}

extern "C" void kernel_launch(void* const* d_in, const int* in_sizes, int n_in,
                              void* d_out, int out_size, void* d_ws, size_t ws_size,
                              hipStream_t stream)
{
    const float* x    = (const float*)d_in[0];
    const int*   eidx = (const int*)d_in[1];      // JAX w/o x64 -> int32. [2][E]
    const float* W1 = (const float*)d_in[2]; const float* b1 = (const float*)d_in[3];
    const float* W2 = (const float*)d_in[4]; const float* b2 = (const float*)d_in[5];
    const float* W3 = (const float*)d_in[6]; const float* b3 = (const float*)d_in[7];
    const float* W4 = (const float*)d_in[8]; const float* b4 = (const float*)d_in[9];

    const int M = in_sizes[0] / 512;     // 20000 nodes
    const int E = in_sizes[1] / 2;       // 320000 edges
    const int DI = 512, DH = 512, DO = 256;

    const int* srcI = eidx;
    const int* dstI = eidx + E;

    // workspace layout
    float* dinv = (float*)d_ws;                              // 20000 f32 (128KB slot)
    float* bufA = (float*)((char*)d_ws + (1 << 17));         // 20000*512 f32
    float* bufB = bufA + (size_t)M * DH;
    float* bufC = bufB + (size_t)M * DH;
    float* out  = (float*)d_out;                             // 20000*256 f32

    const int gN   = (M + THREADS - 1) / THREADS;            // node-wise grids
    const int gE   = (E + THREADS - 1) / THREADS;
    const dim3 gemmH((M + 63) / 64, DH / 64);
    const dim3 gemmO((M + 63) / 64, DO / 64);

    // degrees -> dinv (recomputed every call; no caching allowed)
    k_fill1<<<gN, THREADS, 0, stream>>>(dinv, M);
    k_deg  <<<gE, THREADS, 0, stream>>>(dstI, dinv, E, M);
    k_dinv <<<gN, THREADS, 0, stream>>>(dinv, M);

    // Layer 1: H0 = x ; Lin->bufA, Agg->bufB
    k_gemm<<<gemmH, THREADS, 0, stream>>>(x, W1, bufA, bufB, dinv, M, DH, DI);
    k_edge<<<2048, THREADS, 0, stream>>>(bufA, bufB, srcI, dstI, dinv, E, DH, 7, M);
    k_bias_relu<<<2048, THREADS, 0, stream>>>(bufB, b1, (long long)M * DH / 4, 127);

    // Layer 2: H1 = bufB ; Lin->bufA, Agg->bufC
    k_gemm<<<gemmH, THREADS, 0, stream>>>(bufB, W2, bufA, bufC, dinv, M, DH, DH);
    k_edge<<<2048, THREADS, 0, stream>>>(bufA, bufC, srcI, dstI, dinv, E, DH, 7, M);
    k_bias_relu<<<2048, THREADS, 0, stream>>>(bufC, b2, (long long)M * DH / 4, 127);

    // Layer 3: H2 = bufC ; Lin->bufA, Agg->bufB
    k_gemm<<<gemmH, THREADS, 0, stream>>>(bufC, W3, bufA, bufB, dinv, M, DH, DH);
    k_edge<<<2048, THREADS, 0, stream>>>(bufA, bufB, srcI, dstI, dinv, E, DH, 7, M);
    k_bias_relu<<<2048, THREADS, 0, stream>>>(bufB, b3, (long long)M * DH / 4, 127);

    // Layer 4: H3 = bufB ; Lin->bufA, Agg->d_out (exactly M*256 f32)
    k_gemm<<<gemmO, THREADS, 0, stream>>>(bufB, W4, bufA, out, dinv, M, DO, DH);
    k_edge<<<2048, THREADS, 0, stream>>>(bufA, out, srcI, dstI, dinv, E, DO, 6, M);
    k_softmax_bias<<<(M + 3) / 4, THREADS, 0, stream>>>(out, b4, M);
}

// Round 2
// 917.098 us; speedup vs baseline: 8.7756x; 8.7756x over previous
//
#include <hip/hip_runtime.h>
#include <hip/hip_bf16.h>

// ---------------------------------------------------------------------------
// GCN forward, round 2: CSR-gather aggregation (no f32 atomics).
// Per call:
//   cnt[dst]++  ->  scan -> row_ptr/cursor  ->  fill col/wgt (CSR by dst)
//   per layer: k_gemm (Lin = H @ W^T)
//              k_agg  (one wave per dst row: self-loop + gather-sum neighbors,
//                      + bias + ReLU fused; layer 4 raw -> softmax kernel)
// ---------------------------------------------------------------------------

#define THREADS 256

__global__ void k_zero_int(int* __restrict__ p, int n) {
    int i = blockIdx.x * blockDim.x + threadIdx.x;
    if (i < n) p[i] = 0;
}

__global__ void k_count(const int* __restrict__ dst, int* __restrict__ cnt, int E, int n) {
    int i = blockIdx.x * blockDim.x + threadIdx.x;
    if (i < E) {
        int d = dst[i];
        if ((unsigned)d < (unsigned)n) atomicAdd(&cnt[d], 1);
    }
}

__global__ void k_dinv(const int* __restrict__ cnt, float* __restrict__ dinv, int n) {
    int i = blockIdx.x * blockDim.x + threadIdx.x;
    if (i < n) dinv[i] = rsqrtf((float)(cnt[i] + 1));   // +1 self-loop
}

// Exclusive scan of cnt[0..n) -> row_ptr, cursor. Single block, 1024 threads.
__global__ __launch_bounds__(1024) void k_scan(const int* __restrict__ cnt,
                                               int* __restrict__ row_ptr,
                                               int* __restrict__ cursor, int n)
{
    __shared__ int sm[1024];
    const int t = threadIdx.x;
    const int chunk = (n + 1023) >> 10;
    const int lo = t * chunk, hi = min(n, lo + chunk);
    int s = 0;
    for (int i = lo; i < hi; ++i) s += cnt[i];
    sm[t] = s;
    __syncthreads();
    for (int off = 1; off < 1024; off <<= 1) {
        int v = (t >= off) ? sm[t - off] : 0;
        __syncthreads();
        sm[t] += v;
        __syncthreads();
    }
    int run = sm[t] - s;                       // exclusive base
    for (int i = lo; i < hi; ++i) {
        row_ptr[i] = run;
        cursor[i]  = run;
        run += cnt[i];
    }
}

__global__ void k_fill(const int* __restrict__ src, const int* __restrict__ dst,
                       const float* __restrict__ dinv, int* __restrict__ cursor,
                       int* __restrict__ col, float* __restrict__ wgt, int E, int n)
{
    int i = blockIdx.x * blockDim.x + threadIdx.x;
    if (i < E) {
        int s = src[i], d = dst[i];
        if ((unsigned)s >= (unsigned)n || (unsigned)d >= (unsigned)n) return;
        int pos = atomicAdd(&cursor[d], 1);
        col[pos] = s;
        wgt[pos] = dinv[s];
    }
}

// C = A(MxK) @ W(NxK)^T -> Lin. BM=BN=64, BK=32, 256 threads, 4x4/thread.
__global__ __launch_bounds__(256) void k_gemm(
    const float* __restrict__ A, const float* __restrict__ W,
    float* __restrict__ Lin, int M, int N, int K)
{
    __shared__ float As[32][68];
    __shared__ float Bs[32][68];

    const int tid = threadIdx.x;
    const int m0 = blockIdx.x * 64;
    const int n0 = blockIdx.y * 64;
    const int tx = tid & 15;
    const int ty = tid >> 4;

    float acc[4][4] = {};

    for (int k0 = 0; k0 < K; k0 += 32) {
#pragma unroll
        for (int l = 0; l < 2; ++l) {
            int f   = tid + l * 256;
            int row = f >> 3;
            int c4  = f & 7;
            int m   = m0 + row;
            float4 v = make_float4(0.f, 0.f, 0.f, 0.f);
            if (m < M) v = *(const float4*)(A + (size_t)m * K + k0 + c4 * 4);
            As[c4 * 4 + 0][row] = v.x;
            As[c4 * 4 + 1][row] = v.y;
            As[c4 * 4 + 2][row] = v.z;
            As[c4 * 4 + 3][row] = v.w;
            float4 w = *(const float4*)(W + (size_t)(n0 + row) * K + k0 + c4 * 4);
            Bs[c4 * 4 + 0][row] = w.x;
            Bs[c4 * 4 + 1][row] = w.y;
            Bs[c4 * 4 + 2][row] = w.z;
            Bs[c4 * 4 + 3][row] = w.w;
        }
        __syncthreads();

#pragma unroll
        for (int k = 0; k < 32; ++k) {
            float a[4], b[4];
#pragma unroll
            for (int i = 0; i < 4; ++i) a[i] = As[k][ty * 4 + i];
#pragma unroll
            for (int j = 0; j < 4; ++j) b[j] = Bs[k][tx * 4 + j];
#pragma unroll
            for (int i = 0; i < 4; ++i)
#pragma unroll
                for (int j = 0; j < 4; ++j) acc[i][j] += a[i] * b[j];
        }
        __syncthreads();
    }

#pragma unroll
    for (int i = 0; i < 4; ++i) {
        int m = m0 + ty * 4 + i;
        if (m >= M) break;
        *(float4*)(Lin + (size_t)m * N + n0 + tx * 4) =
            make_float4(acc[i][0], acc[i][1], acc[i][2], acc[i][3]);
    }
}

// Gather-aggregate: Out[r] = dinv[r]*( sum_e wgt[e]*Lin[col[e]] ) + dinv[r]^2*Lin[r]
//                   (+ bias, ReLU when FUSE_BIAS_RELU). One wave per row.
// D = NV4 * 256 floats per row (NV4 float4 per lane).
template <int NV4, bool FUSE_BIAS_RELU>
__global__ __launch_bounds__(256) void k_agg(
    const float* __restrict__ Lin, float* __restrict__ Out,
    const int* __restrict__ row_ptr, const int* __restrict__ cnt,
    const int* __restrict__ col, const float* __restrict__ wgt,
    const float* __restrict__ dinv, const float* __restrict__ bias, int M)
{
    const int D = NV4 * 256;
    const int row = blockIdx.x * 4 + (threadIdx.x >> 6);
    if (row >= M) return;
    const int lane = threadIdx.x & 63;

    const float dr = dinv[row];
    const int beg = row_ptr[row];
    const int num = cnt[row];

    float4 acc[NV4];
#pragma unroll
    for (int j = 0; j < NV4; ++j) acc[j] = make_float4(0.f, 0.f, 0.f, 0.f);

    for (int e = 0; e < num; ++e) {
        const int   s = col[beg + e];
        const float w = wgt[beg + e];
        const float4* p = (const float4*)(Lin + (size_t)s * D) + lane;
#pragma unroll
        for (int j = 0; j < NV4; ++j) {
            float4 v = p[j * 64];
            acc[j].x += w * v.x;
            acc[j].y += w * v.y;
            acc[j].z += w * v.z;
            acc[j].w += w * v.w;
        }
    }

    const float4* ps = (const float4*)(Lin + (size_t)row * D) + lane;
    float4*       po = (float4*)(Out + (size_t)row * D) + lane;
    const float   dr2 = dr * dr;
#pragma unroll
    for (int j = 0; j < NV4; ++j) {
        float4 v = ps[j * 64];
        float4 o;
        o.x = acc[j].x * dr + dr2 * v.x;
        o.y = acc[j].y * dr + dr2 * v.y;
        o.z = acc[j].z * dr + dr2 * v.z;
        o.w = acc[j].w * dr + dr2 * v.w;
        if (FUSE_BIAS_RELU) {
            const float4 b = ((const float4*)bias)[j * 64 + lane];
            o.x = fmaxf(o.x + b.x, 0.f);
            o.y = fmaxf(o.y + b.y, 0.f);
            o.z = fmaxf(o.z + b.z, 0.f);
            o.w = fmaxf(o.w + b.w, 0.f);
        }
        po[j * 64] = o;
    }
}

// In-place softmax over rows of 256 (+ bias). One wave per row.
__global__ __launch_bounds__(256) void k_softmax_bias(float* __restrict__ IO,
                                                      const float* __restrict__ bias, int M)
{
    int row  = blockIdx.x * 4 + (threadIdx.x >> 6);
    int lane = threadIdx.x & 63;
    if (row >= M) return;
    float* p = IO + (size_t)row * 256 + lane * 4;
    float4 v = *(float4*)p;
    const float4 b = *(const float4*)(bias + lane * 4);
    v.x += b.x; v.y += b.y; v.z += b.z; v.w += b.w;
    float m = fmaxf(fmaxf(v.x, v.y), fmaxf(v.z, v.w));
#pragma unroll
    for (int off = 32; off > 0; off >>= 1) m = fmaxf(m, __shfl_xor(m, off));
    float e0 = expf(v.x - m), e1 = expf(v.y - m), e2 = expf(v.z - m), e3 = expf(v.w - m);
    float s = e0 + e1 + e2 + e3;
#pragma unroll
    for (int off = 32; off > 0; off >>= 1) s += __shfl_xor(s, off);
    float inv = 1.0f / s;
    v.x = e0 * inv; v.y = e1 * inv; v.z = e2 * inv; v.w = e3 * inv;
    *(float4*)p = v;
}

extern "C" void kernel_launch(void* const* d_in, const int* in_sizes, int n_in,
                              void* d_out, int out_size, void* d_ws, size_t ws_size,
                              hipStream_t stream)
{
    const float* x    = (const float*)d_in[0];
    const int*   eidx = (const int*)d_in[1];      // int32 [2][E]
    const float* W1 = (const float*)d_in[2]; const float* b1 = (const float*)d_in[3];
    const float* W2 = (const float*)d_in[4]; const float* b2 = (const float*)d_in[5];
    const float* W3 = (const float*)d_in[6]; const float* b3 = (const float*)d_in[7];
    const float* W4 = (const float*)d_in[8]; const float* b4 = (const float*)d_in[9];

    const int M = in_sizes[0] / 512;     // 20000
    const int E = in_sizes[1] / 2;       // 320000
    const int DH = 512, DO = 256;

    const int* srcI = eidx;
    const int* dstI = eidx + E;

    // workspace layout (128 KiB-aligned slots)
    char* ws = (char*)d_ws;
    int*   cnt     = (int*)  (ws + 0);                 // 20000 i32
    int*   row_ptr = (int*)  (ws + (1 << 17));         // 20000 i32
    int*   cursor  = (int*)  (ws + (2 << 17));         // 20000 i32
    float* dinv    = (float*)(ws + (3 << 17));         // 20000 f32
    int*   col     = (int*)  (ws + (4 << 17));         // 320000 i32
    float* wgt     = (float*)(ws + (4 << 17) + (320000 * 4 + 4096)); // 320000 f32
    float* bufA    = (float*)(ws + (4 << 20));         // 20000*512 f32 (Lin)
    float* bufB    = bufA + (size_t)M * DH;            // 20000*512 f32 (H)
    float* out     = (float*)d_out;

    const int gN = (M + THREADS - 1) / THREADS;
    const int gE = (E + THREADS - 1) / THREADS;
    const dim3 gemmH((M + 63) / 64, DH / 64);
    const dim3 gemmO((M + 63) / 64, DO / 64);
    const int gAgg = (M + 3) / 4;

    // --- CSR build (per call; deterministic up to fp-sum order) ---
    k_zero_int<<<gN, THREADS, 0, stream>>>(cnt, M);
    k_count   <<<gE, THREADS, 0, stream>>>(dstI, cnt, E, M);
    k_dinv    <<<gN, THREADS, 0, stream>>>(cnt, dinv, M);
    k_scan    <<<1, 1024, 0, stream>>>(cnt, row_ptr, cursor, M);
    k_fill    <<<gE, THREADS, 0, stream>>>(srcI, dstI, dinv, cursor, col, wgt, E, M);

    // --- Layer 1 ---
    k_gemm<<<gemmH, THREADS, 0, stream>>>(x, W1, bufA, M, DH, 512);
    k_agg<2, true><<<gAgg, THREADS, 0, stream>>>(bufA, bufB, row_ptr, cnt, col, wgt, dinv, b1, M);
    // --- Layer 2 ---
    k_gemm<<<gemmH, THREADS, 0, stream>>>(bufB, W2, bufA, M, DH, DH);
    k_agg<2, true><<<gAgg, THREADS, 0, stream>>>(bufA, bufB, row_ptr, cnt, col, wgt, dinv, b2, M);
    // --- Layer 3 ---
    k_gemm<<<gemmH, THREADS, 0, stream>>>(bufB, W3, bufA, M, DH, DH);
    k_agg<2, true><<<gAgg, THREADS, 0, stream>>>(bufA, bufB, row_ptr, cnt, col, wgt, dinv, b3, M);
    // --- Layer 4 ---
    k_gemm<<<gemmO, THREADS, 0, stream>>>(bufB, W4, bufA, M, DO, DH);
    k_agg<1, false><<<gAgg, THREADS, 0, stream>>>(bufA, out, row_ptr, cnt, col, wgt, dinv, nullptr, M);
    k_softmax_bias<<<gAgg, THREADS, 0, stream>>>(out, b4, M);
}

// Round 3
// 641.013 us; speedup vs baseline: 12.5553x; 1.4307x over previous
//
#include <hip/hip_runtime.h>
#include <hip/hip_bf16.h>

// ---------------------------------------------------------------------------
// GCN forward, round 3: split-bf16 MFMA GEMM + CSR-gather aggregation.
//   f32 operand a = hi(bf16) + lo(bf16);  C = Ah*Bh + Al*Bh + Ah*Bl (f32 acc)
//   k_mfma: 128x64 tile, BK=64, 4 waves, global_load_lds(16B) staging with
//           XOR-8 swizzle pre-applied on the GLOBAL source (linear LDS dest).
//   k_agg:  gather-aggregate, emits next layer's hi/lo bf16 pair fused.
// ---------------------------------------------------------------------------

#define THREADS 256

typedef __bf16 bf16_t;
typedef __bf16 bf16x8 __attribute__((ext_vector_type(8)));
typedef __bf16 bf16x4 __attribute__((ext_vector_type(4)));
typedef float  f32x4  __attribute__((ext_vector_type(4)));

typedef const __attribute__((address_space(1))) void* gas_ptr;
typedef __attribute__((address_space(3))) void*       las_ptr;

// ------------------------------ CSR build ----------------------------------

__global__ void k_zero_int(int* __restrict__ p, int n) {
    int i = blockIdx.x * blockDim.x + threadIdx.x;
    if (i < n) p[i] = 0;
}

__global__ void k_count(const int* __restrict__ dst, int* __restrict__ cnt, int E, int n) {
    int i = blockIdx.x * blockDim.x + threadIdx.x;
    if (i < E) {
        int d = dst[i];
        if ((unsigned)d < (unsigned)n) atomicAdd(&cnt[d], 1);
    }
}

__global__ void k_dinv(const int* __restrict__ cnt, float* __restrict__ dinv, int n) {
    int i = blockIdx.x * blockDim.x + threadIdx.x;
    if (i < n) dinv[i] = rsqrtf((float)(cnt[i] + 1));   // +1 self-loop
}

__global__ __launch_bounds__(1024) void k_scan(const int* __restrict__ cnt,
                                               int* __restrict__ row_ptr,
                                               int* __restrict__ cursor, int n)
{
    __shared__ int sm[1024];
    const int t = threadIdx.x;
    const int chunk = (n + 1023) >> 10;
    const int lo = t * chunk, hi = min(n, lo + chunk);
    int s = 0;
    for (int i = lo; i < hi; ++i) s += cnt[i];
    sm[t] = s;
    __syncthreads();
    for (int off = 1; off < 1024; off <<= 1) {
        int v = (t >= off) ? sm[t - off] : 0;
        __syncthreads();
        sm[t] += v;
        __syncthreads();
    }
    int run = sm[t] - s;
    for (int i = lo; i < hi; ++i) {
        row_ptr[i] = run;
        cursor[i]  = run;
        run += cnt[i];
    }
}

__global__ void k_fill(const int* __restrict__ src, const int* __restrict__ dst,
                       int* __restrict__ cursor, int* __restrict__ col, int E, int n)
{
    int i = blockIdx.x * blockDim.x + threadIdx.x;
    if (i < E) {
        int s = src[i], d = dst[i];
        if ((unsigned)s >= (unsigned)n || (unsigned)d >= (unsigned)n) return;
        int pos = atomicAdd(&cursor[d], 1);
        col[pos] = s;
    }
}

// --------------------------- f32 -> hi/lo bf16 -----------------------------

__global__ void k_split(const float* __restrict__ in, bf16_t* __restrict__ hi,
                        bf16_t* __restrict__ lo, int n4)
{
    int i = blockIdx.x * blockDim.x + threadIdx.x;
    const int stride = gridDim.x * blockDim.x;
    for (; i < n4; i += stride) {
        float4 v = ((const float4*)in)[i];
        bf16x4 h, l;
        h[0] = (bf16_t)v.x; l[0] = (bf16_t)(v.x - (float)h[0]);
        h[1] = (bf16_t)v.y; l[1] = (bf16_t)(v.y - (float)h[1]);
        h[2] = (bf16_t)v.z; l[2] = (bf16_t)(v.z - (float)h[2]);
        h[3] = (bf16_t)v.w; l[3] = (bf16_t)(v.w - (float)h[3]);
        ((bf16x4*)hi)[i] = h;
        ((bf16x4*)lo)[i] = l;
    }
}

// ------------------------ split-bf16 MFMA GEMM -----------------------------
// C(MxN, f32) = (Ah+Al)(MxK) @ (Bh+Bl)(NxK)^T, dropping Al*Bl.
// Tile 128(M) x 64(N), BK=64, 256 threads = 4 waves (2m x 2n), 64x32 each.
// LDS panels stored swizzled: element (row,kb) at slot row*8 + (kb^(row&7)),
// achieved by inverse-permuting the GLOBAL source (global_load_lds is linear).
__global__ __launch_bounds__(256, 3) void k_mfma(
    const bf16_t* __restrict__ Ah, const bf16_t* __restrict__ Al,
    const bf16_t* __restrict__ Bh, const bf16_t* __restrict__ Bl,
    float* __restrict__ C, int M, int N, int K)
{
    __shared__ bf16_t sAh[128 * 64];
    __shared__ bf16_t sAl[128 * 64];
    __shared__ bf16_t sBh[64 * 64];
    __shared__ bf16_t sBl[64 * 64];

    const int tid  = threadIdx.x;
    const int lane = tid & 63;
    const int wid  = tid >> 6;
    const int m0   = blockIdx.x * 128;
    const int n0   = blockIdx.y * 64;
    const int wm   = (wid >> 1) * 64;   // wave m-offset in tile
    const int wn   = (wid & 1) * 32;    // wave n-offset in tile

    f32x4 acc[4][2] = {};

    // staging slots (16B per thread per issue); fixed across K-steps
    int aoff[4], aslot[4];
#pragma unroll
    for (int i = 0; i < 4; ++i) {
        int slot = i * 256 + tid;
        int row  = slot >> 3, s = slot & 7;
        int kb   = s ^ (row & 7);            // inverse swizzle on source
        int gm   = m0 + row; if (gm > M - 1) gm = M - 1;   // clamp tail rows
        aoff[i]  = gm * K + kb * 8;
        aslot[i] = slot * 8;
    }
    int boff[2], bslot[2];
#pragma unroll
    for (int i = 0; i < 2; ++i) {
        int slot = i * 256 + tid;
        int row  = slot >> 3, s = slot & 7;
        int kb   = s ^ (row & 7);
        boff[i]  = (n0 + row) * K + kb * 8;
        bslot[i] = slot * 8;
    }

    for (int k0 = 0; k0 < K; k0 += 64) {
#pragma unroll
        for (int i = 0; i < 4; ++i) {
            __builtin_amdgcn_global_load_lds((gas_ptr)(Ah + aoff[i] + k0),
                                             (las_ptr)(sAh + aslot[i]), 16, 0, 0);
            __builtin_amdgcn_global_load_lds((gas_ptr)(Al + aoff[i] + k0),
                                             (las_ptr)(sAl + aslot[i]), 16, 0, 0);
        }
#pragma unroll
        for (int i = 0; i < 2; ++i) {
            __builtin_amdgcn_global_load_lds((gas_ptr)(Bh + boff[i] + k0),
                                             (las_ptr)(sBh + bslot[i]), 16, 0, 0);
            __builtin_amdgcn_global_load_lds((gas_ptr)(Bl + boff[i] + k0),
                                             (las_ptr)(sBl + bslot[i]), 16, 0, 0);
        }
        __syncthreads();

#pragma unroll
        for (int ks = 0; ks < 2; ++ks) {
            const int kb = ks * 4 + (lane >> 4);
            bf16x8 ah[4], al[4], bh[2], bl[2];
#pragma unroll
            for (int mf = 0; mf < 4; ++mf) {
                int row  = wm + mf * 16 + (lane & 15);
                int slot = row * 8 + (kb ^ (row & 7));
                ah[mf] = *(const bf16x8*)(sAh + slot * 8);
                al[mf] = *(const bf16x8*)(sAl + slot * 8);
            }
#pragma unroll
            for (int nf = 0; nf < 2; ++nf) {
                int row  = wn + nf * 16 + (lane & 15);
                int slot = row * 8 + (kb ^ (row & 7));
                bh[nf] = *(const bf16x8*)(sBh + slot * 8);
                bl[nf] = *(const bf16x8*)(sBl + slot * 8);
            }
#pragma unroll
            for (int mf = 0; mf < 4; ++mf)
#pragma unroll
                for (int nf = 0; nf < 2; ++nf) {
                    acc[mf][nf] = __builtin_amdgcn_mfma_f32_16x16x32_bf16(
                        ah[mf], bh[nf], acc[mf][nf], 0, 0, 0);
                    acc[mf][nf] = __builtin_amdgcn_mfma_f32_16x16x32_bf16(
                        al[mf], bh[nf], acc[mf][nf], 0, 0, 0);
                    acc[mf][nf] = __builtin_amdgcn_mfma_f32_16x16x32_bf16(
                        ah[mf], bl[nf], acc[mf][nf], 0, 0, 0);
                }
        }
        __syncthreads();
    }

    // C/D layout: col = lane&15, row = (lane>>4)*4 + reg  [learn_hip m89/m91]
    const int cn = lane & 15;
    const int cr = (lane >> 4) * 4;
#pragma unroll
    for (int mf = 0; mf < 4; ++mf) {
#pragma unroll
        for (int r = 0; r < 4; ++r) {
            const int m = m0 + wm + mf * 16 + cr + r;
            if (m < M) {
                float* cp = C + (size_t)m * N + n0 + wn + cn;
                cp[0]  = acc[mf][0][r];
                cp[16] = acc[mf][1][r];
            }
        }
    }
}

// --------------------------- gather-aggregate ------------------------------
// Out[r] = dinv[r]*( sum_e dinv[col[e]]*Lin[col[e]] ) + dinv[r]^2*Lin[r]
// MODE 0: write raw f32 to OutF (layer 4).  MODE 1: +bias, ReLU, write hi/lo.
template <int NV4, int MODE>
__global__ __launch_bounds__(256) void k_agg(
    const float* __restrict__ Lin, float* __restrict__ OutF,
    bf16_t* __restrict__ OutH, bf16_t* __restrict__ OutL,
    const int* __restrict__ row_ptr, const int* __restrict__ cnt,
    const int* __restrict__ col, const float* __restrict__ dinv,
    const float* __restrict__ bias, int M)
{
    const int D = NV4 * 256;
    const int row = blockIdx.x * 4 + (threadIdx.x >> 6);
    if (row >= M) return;
    const int lane = threadIdx.x & 63;

    const float dr  = dinv[row];
    const int   beg = row_ptr[row];
    const int   num = cnt[row];

    float4 acc[NV4];
#pragma unroll
    for (int j = 0; j < NV4; ++j) acc[j] = make_float4(0.f, 0.f, 0.f, 0.f);

    for (int e = 0; e < num; ++e) {
        const int   s = col[beg + e];
        const float w = dinv[s];
        const float4* p = (const float4*)(Lin + (size_t)s * D) + lane;
#pragma unroll
        for (int j = 0; j < NV4; ++j) {
            float4 v = p[j * 64];
            acc[j].x += w * v.x;
            acc[j].y += w * v.y;
            acc[j].z += w * v.z;
            acc[j].w += w * v.w;
        }
    }

    const float4* ps = (const float4*)(Lin + (size_t)row * D) + lane;
    const float dr2 = dr * dr;
#pragma unroll
    for (int j = 0; j < NV4; ++j) {
        float4 v = ps[j * 64];
        float4 o;
        o.x = acc[j].x * dr + dr2 * v.x;
        o.y = acc[j].y * dr + dr2 * v.y;
        o.z = acc[j].z * dr + dr2 * v.z;
        o.w = acc[j].w * dr + dr2 * v.w;
        if (MODE == 1) {
            const float4 b = ((const float4*)bias)[j * 64 + lane];
            o.x = fmaxf(o.x + b.x, 0.f);
            o.y = fmaxf(o.y + b.y, 0.f);
            o.z = fmaxf(o.z + b.z, 0.f);
            o.w = fmaxf(o.w + b.w, 0.f);
            bf16x4 h, l;
            h[0] = (bf16_t)o.x; l[0] = (bf16_t)(o.x - (float)h[0]);
            h[1] = (bf16_t)o.y; l[1] = (bf16_t)(o.y - (float)h[1]);
            h[2] = (bf16_t)o.z; l[2] = (bf16_t)(o.z - (float)h[2]);
            h[3] = (bf16_t)o.w; l[3] = (bf16_t)(o.w - (float)h[3]);
            const size_t eo = (size_t)row * D + lane * 4 + j * 256;
            *(bf16x4*)(OutH + eo) = h;
            *(bf16x4*)(OutL + eo) = l;
        } else {
            ((float4*)(OutF + (size_t)row * D))[lane + j * 64] = o;
        }
    }
}

// ------------------------------- softmax -----------------------------------

__global__ __launch_bounds__(256) void k_softmax_bias(float* __restrict__ IO,
                                                      const float* __restrict__ bias, int M)
{
    int row  = blockIdx.x * 4 + (threadIdx.x >> 6);
    int lane = threadIdx.x & 63;
    if (row >= M) return;
    float* p = IO + (size_t)row * 256 + lane * 4;
    float4 v = *(float4*)p;
    const float4 b = *(const float4*)(bias + lane * 4);
    v.x += b.x; v.y += b.y; v.z += b.z; v.w += b.w;
    float m = fmaxf(fmaxf(v.x, v.y), fmaxf(v.z, v.w));
#pragma unroll
    for (int off = 32; off > 0; off >>= 1) m = fmaxf(m, __shfl_xor(m, off));
    float e0 = expf(v.x - m), e1 = expf(v.y - m), e2 = expf(v.z - m), e3 = expf(v.w - m);
    float s = e0 + e1 + e2 + e3;
#pragma unroll
    for (int off = 32; off > 0; off >>= 1) s += __shfl_xor(s, off);
    float inv = 1.0f / s;
    v.x = e0 * inv; v.y = e1 * inv; v.z = e2 * inv; v.w = e3 * inv;
    *(float4*)p = v;
}

// ------------------------------- launcher ----------------------------------

extern "C" void kernel_launch(void* const* d_in, const int* in_sizes, int n_in,
                              void* d_out, int out_size, void* d_ws, size_t ws_size,
                              hipStream_t stream)
{
    const float* x    = (const float*)d_in[0];
    const int*   eidx = (const int*)d_in[1];      // int32 [2][E]
    const float* W1 = (const float*)d_in[2]; const float* b1 = (const float*)d_in[3];
    const float* W2 = (const float*)d_in[4]; const float* b2 = (const float*)d_in[5];
    const float* W3 = (const float*)d_in[6]; const float* b3 = (const float*)d_in[7];
    const float* W4 = (const float*)d_in[8]; const float* b4 = (const float*)d_in[9];

    const int M = in_sizes[0] / 512;     // 20000
    const int E = in_sizes[1] / 2;       // 320000
    const int DH = 512, DO = 256;

    const int* srcI = eidx;
    const int* dstI = eidx + E;

    // ---- workspace layout (bytes) ----
    char* ws = (char*)d_ws;
    int*    cnt     = (int*)   (ws + 0);                  // 80KB
    int*    row_ptr = (int*)   (ws + (1 << 17));
    int*    cursor  = (int*)   (ws + (2 << 17));
    float*  dinv    = (float*) (ws + (3 << 17));
    int*    col     = (int*)   (ws + (4 << 17));          // 1.28MB @512K
    bf16_t* W1h = (bf16_t*)(ws + 2097152);
    bf16_t* W1l = (bf16_t*)(ws + 2621440);
    bf16_t* W2h = (bf16_t*)(ws + 3145728);
    bf16_t* W2l = (bf16_t*)(ws + 3670016);
    bf16_t* W3h = (bf16_t*)(ws + 4194304);
    bf16_t* W3l = (bf16_t*)(ws + 4718592);
    bf16_t* W4h = (bf16_t*)(ws + 5242880);
    bf16_t* W4l = (bf16_t*)(ws + 5505024);
    const size_t HALF = (size_t)20000 * 512 * 2;          // 20.48MB
    bf16_t* PH  = (bf16_t*)(ws + 6291456);                // activation pair (hi)
    bf16_t* PL  = (bf16_t*)(ws + 6291456 + HALF);         // activation pair (lo)
    float*  Lin = (float*) (ws + 6291456 + 2 * HALF);     // f32 GEMM out, 41MB
    float*  out = (float*)d_out;

    const int gN = (M + THREADS - 1) / THREADS;
    const int gE = (E + THREADS - 1) / THREADS;
    const dim3 gemmH((M + 127) / 128, DH / 64);
    const dim3 gemmO((M + 127) / 128, DO / 64);
    const int gAgg = (M + 3) / 4;

    // ---- CSR build ----
    k_zero_int<<<gN, THREADS, 0, stream>>>(cnt, M);
    k_count   <<<gE, THREADS, 0, stream>>>(dstI, cnt, E, M);
    k_dinv    <<<gN, THREADS, 0, stream>>>(cnt, dinv, M);
    k_scan    <<<1, 1024, 0, stream>>>(cnt, row_ptr, cursor, M);
    k_fill    <<<gE, THREADS, 0, stream>>>(srcI, dstI, cursor, col, E, M);

    // ---- operand splits ----
    k_split<<<2048, THREADS, 0, stream>>>(x,  PH,  PL,  M * DH / 4);
    k_split<<<256,  THREADS, 0, stream>>>(W1, W1h, W1l, DH * DH / 4);
    k_split<<<256,  THREADS, 0, stream>>>(W2, W2h, W2l, DH * DH / 4);
    k_split<<<256,  THREADS, 0, stream>>>(W3, W3h, W3l, DH * DH / 4);
    k_split<<<128,  THREADS, 0, stream>>>(W4, W4h, W4l, DO * DH / 4);

    // ---- Layer 1 ----
    k_mfma<<<gemmH, THREADS, 0, stream>>>(PH, PL, W1h, W1l, Lin, M, DH, 512);
    k_agg<2, 1><<<gAgg, THREADS, 0, stream>>>(Lin, nullptr, PH, PL, row_ptr, cnt, col, dinv, b1, M);
    // ---- Layer 2 ----
    k_mfma<<<gemmH, THREADS, 0, stream>>>(PH, PL, W2h, W2l, Lin, M, DH, DH);
    k_agg<2, 1><<<gAgg, THREADS, 0, stream>>>(Lin, nullptr, PH, PL, row_ptr, cnt, col, dinv, b2, M);
    // ---- Layer 3 ----
    k_mfma<<<gemmH, THREADS, 0, stream>>>(PH, PL, W3h, W3l, Lin, M, DH, DH);
    k_agg<2, 1><<<gAgg, THREADS, 0, stream>>>(Lin, nullptr, PH, PL, row_ptr, cnt, col, dinv, b3, M);
    // ---- Layer 4 ----
    k_mfma<<<gemmO, THREADS, 0, stream>>>(PH, PL, W4h, W4l, Lin, M, DO, DH);
    k_agg<1, 0><<<gAgg, THREADS, 0, stream>>>(Lin, out, nullptr, nullptr, row_ptr, cnt, col, dinv, nullptr, M);
    k_softmax_bias<<<gAgg, THREADS, 0, stream>>>(out, b4, M);
}

// Round 4
// 595.812 us; speedup vs baseline: 13.5077x; 1.0759x over previous
//
#include <hip/hip_runtime.h>
#include <hip/hip_bf16.h>

// ---------------------------------------------------------------------------
// GCN forward, round 4.
//   k_mfma: split-bf16 MFMA GEMM, 128x128 tile, BK=32, 4 waves (wave 64x64),
//           3:1 MFMA:ds_read density, 32KB LDS (pair), bijective unit-XOR
//           swizzle applied on the GLOBAL source (linear LDS dest).
//   k_agg:  CSR gather-aggregate, 4x unrolled edge loop (8 float4 in flight),
//           fused bias+ReLU+split (hidden) / fused bias+softmax (layer 4).
// ---------------------------------------------------------------------------

#define THREADS 256

typedef __bf16 bf16_t;
typedef __bf16 bf16x8 __attribute__((ext_vector_type(8)));
typedef __bf16 bf16x4 __attribute__((ext_vector_type(4)));
typedef float  f32x4  __attribute__((ext_vector_type(4)));

typedef const __attribute__((address_space(1))) void* gas_ptr;
typedef __attribute__((address_space(3))) void*       las_ptr;

// ------------------------------ CSR build ----------------------------------

__global__ void k_zero_int(int* __restrict__ p, int n) {
    int i = blockIdx.x * blockDim.x + threadIdx.x;
    if (i < n) p[i] = 0;
}

__global__ void k_count(const int* __restrict__ dst, int* __restrict__ cnt, int E, int n) {
    int i = blockIdx.x * blockDim.x + threadIdx.x;
    if (i < E) {
        int d = dst[i];
        if ((unsigned)d < (unsigned)n) atomicAdd(&cnt[d], 1);
    }
}

__global__ void k_dinv(const int* __restrict__ cnt, float* __restrict__ dinv, int n) {
    int i = blockIdx.x * blockDim.x + threadIdx.x;
    if (i < n) dinv[i] = rsqrtf((float)(cnt[i] + 1));   // +1 self-loop
}

__global__ __launch_bounds__(1024) void k_scan(const int* __restrict__ cnt,
                                               int* __restrict__ row_ptr,
                                               int* __restrict__ cursor, int n)
{
    __shared__ int sm[1024];
    const int t = threadIdx.x;
    const int chunk = (n + 1023) >> 10;
    const int lo = t * chunk, hi = min(n, lo + chunk);
    int s = 0;
    for (int i = lo; i < hi; ++i) s += cnt[i];
    sm[t] = s;
    __syncthreads();
    for (int off = 1; off < 1024; off <<= 1) {
        int v = (t >= off) ? sm[t - off] : 0;
        __syncthreads();
        sm[t] += v;
        __syncthreads();
    }
    int run = sm[t] - s;
    for (int i = lo; i < hi; ++i) {
        row_ptr[i] = run;
        cursor[i]  = run;
        run += cnt[i];
    }
}

__global__ void k_fill(const int* __restrict__ src, const int* __restrict__ dst,
                       int* __restrict__ cursor, int* __restrict__ col, int E, int n)
{
    int i = blockIdx.x * blockDim.x + threadIdx.x;
    if (i < E) {
        int s = src[i], d = dst[i];
        if ((unsigned)s >= (unsigned)n || (unsigned)d >= (unsigned)n) return;
        int pos = atomicAdd(&cursor[d], 1);
        col[pos] = s;
    }
}

// --------------------------- f32 -> hi/lo bf16 -----------------------------

__global__ void k_split(const float* __restrict__ in, bf16_t* __restrict__ hi,
                        bf16_t* __restrict__ lo, int n4)
{
    int i = blockIdx.x * blockDim.x + threadIdx.x;
    const int stride = gridDim.x * blockDim.x;
    for (; i < n4; i += stride) {
        float4 v = ((const float4*)in)[i];
        bf16x4 h, l;
        h[0] = (bf16_t)v.x; l[0] = (bf16_t)(v.x - (float)h[0]);
        h[1] = (bf16_t)v.y; l[1] = (bf16_t)(v.y - (float)h[1]);
        h[2] = (bf16_t)v.z; l[2] = (bf16_t)(v.z - (float)h[2]);
        h[3] = (bf16_t)v.w; l[3] = (bf16_t)(v.w - (float)h[3]);
        ((bf16x4*)hi)[i] = h;
        ((bf16x4*)lo)[i] = l;
    }
}

// ------------------------ split-bf16 MFMA GEMM -----------------------------
// C(MxN, f32) = (Ah+Al)(MxK) @ (Bh+Bl)(NxK)^T, dropping Al*Bl.
// Tile 128(M) x 128(N), BK=32, 256 threads = 4 waves (2m x 2n), 64x64 each.
// Panel layout (128 rows x 4 16B-slots): 2-row units of 8 slots;
// slot-in-unit = u ^ (unit&7) with u = (row&1)*4 + kb. Bijective; ds_read
// of a fixed kb across 16 rows -> 8 distinct slots, 2 rows each (2-way, free).
// Inverse permutation applied on the GLOBAL source; LDS dest stays linear.
__global__ __launch_bounds__(256) void k_mfma(
    const bf16_t* __restrict__ Ah, const bf16_t* __restrict__ Al,
    const bf16_t* __restrict__ Bh, const bf16_t* __restrict__ Bl,
    float* __restrict__ C, int M, int N, int K)
{
    __shared__ bf16_t sAh[128 * 32];
    __shared__ bf16_t sAl[128 * 32];
    __shared__ bf16_t sBh[128 * 32];
    __shared__ bf16_t sBl[128 * 32];

    const int tid  = threadIdx.x;
    const int lane = tid & 63;
    const int wid  = tid >> 6;
    const int m0   = blockIdx.x * 128;
    const int n0   = blockIdx.y * 128;
    const int wm   = (wid >> 1) * 64;
    const int wn   = (wid & 1) * 64;

    f32x4 acc[4][4] = {};

    // staging: issue i covers slots p = i*256+tid; LDS dest linear (p*16B),
    // global source inverse-permuted.
    int asrc[2], bsrc[2], sdst[2];
#pragma unroll
    for (int i = 0; i < 2; ++i) {
        int p    = i * 256 + tid;
        int unit = p >> 3, sl = p & 7;
        int u    = sl ^ (unit & 7);
        int row  = (unit << 1) | (u >> 2);
        int kb   = u & 3;
        int gm   = m0 + row; if (gm >= M) gm = M - 1;   // clamp tail rows
        asrc[i]  = gm * K + kb * 8;
        bsrc[i]  = (n0 + row) * K + kb * 8;
        sdst[i]  = p * 8;                                // bf16 elems
    }

    for (int k0 = 0; k0 < K; k0 += 32) {
#pragma unroll
        for (int i = 0; i < 2; ++i) {
            __builtin_amdgcn_global_load_lds((gas_ptr)(Ah + asrc[i] + k0),
                                             (las_ptr)(sAh + sdst[i]), 16, 0, 0);
            __builtin_amdgcn_global_load_lds((gas_ptr)(Al + asrc[i] + k0),
                                             (las_ptr)(sAl + sdst[i]), 16, 0, 0);
            __builtin_amdgcn_global_load_lds((gas_ptr)(Bh + bsrc[i] + k0),
                                             (las_ptr)(sBh + sdst[i]), 16, 0, 0);
            __builtin_amdgcn_global_load_lds((gas_ptr)(Bl + bsrc[i] + k0),
                                             (las_ptr)(sBl + sdst[i]), 16, 0, 0);
        }
        __syncthreads();

        const int kb = lane >> 4;
        bf16x8 a_h[4], a_l[4], b_h[4], b_l[4];
#pragma unroll
        for (int mf = 0; mf < 4; ++mf) {
            int row  = wm + mf * 16 + (lane & 15);
            int unit = row >> 1;
            int sl   = (((row & 1) << 2) | kb) ^ (unit & 7);
            int off  = (unit * 8 + sl) * 8;
            a_h[mf] = *(const bf16x8*)(sAh + off);
            a_l[mf] = *(const bf16x8*)(sAl + off);
        }
#pragma unroll
        for (int nf = 0; nf < 4; ++nf) {
            int row  = wn + nf * 16 + (lane & 15);
            int unit = row >> 1;
            int sl   = (((row & 1) << 2) | kb) ^ (unit & 7);
            int off  = (unit * 8 + sl) * 8;
            b_h[nf] = *(const bf16x8*)(sBh + off);
            b_l[nf] = *(const bf16x8*)(sBl + off);
        }
#pragma unroll
        for (int mf = 0; mf < 4; ++mf)
#pragma unroll
            for (int nf = 0; nf < 4; ++nf) {
                acc[mf][nf] = __builtin_amdgcn_mfma_f32_16x16x32_bf16(
                    a_h[mf], b_h[nf], acc[mf][nf], 0, 0, 0);
                acc[mf][nf] = __builtin_amdgcn_mfma_f32_16x16x32_bf16(
                    a_l[mf], b_h[nf], acc[mf][nf], 0, 0, 0);
                acc[mf][nf] = __builtin_amdgcn_mfma_f32_16x16x32_bf16(
                    a_h[mf], b_l[nf], acc[mf][nf], 0, 0, 0);
            }
        __syncthreads();
    }

    // C/D layout: col = lane&15, row = (lane>>4)*4 + reg  [learn_hip m89/m91]
    const int cn = lane & 15;
    const int cr = (lane >> 4) * 4;
#pragma unroll
    for (int mf = 0; mf < 4; ++mf) {
#pragma unroll
        for (int r = 0; r < 4; ++r) {
            const int m = m0 + wm + mf * 16 + cr + r;
            if (m < M) {
                float* cp = C + (size_t)m * N + n0 + wn + cn;
                cp[0]  = acc[mf][0][r];
                cp[16] = acc[mf][1][r];
                cp[32] = acc[mf][2][r];
                cp[48] = acc[mf][3][r];
            }
        }
    }
}

// --------------------------- gather-aggregate ------------------------------
// Out[r] = dinv[r]*( sum_e dinv[col[e]]*Lin[col[e]] ) + dinv[r]^2*Lin[r]
// MODE 1: +bias, ReLU, write hi/lo bf16 pair (hidden layers).
// MODE 0: +bias, softmax over the 256-wide row, write f32 (layer 4).
template <int NV4, int MODE>
__global__ __launch_bounds__(256) void k_agg(
    const float* __restrict__ Lin, float* __restrict__ OutF,
    bf16_t* __restrict__ OutH, bf16_t* __restrict__ OutL,
    const int* __restrict__ row_ptr, const int* __restrict__ cnt,
    const int* __restrict__ col, const float* __restrict__ dinv,
    const float* __restrict__ bias, int M)
{
    const int D = NV4 * 256;
    const int row = blockIdx.x * 4 + (threadIdx.x >> 6);
    if (row >= M) return;
    const int lane = threadIdx.x & 63;

    const float dr  = dinv[row];
    const int   beg = row_ptr[row];
    const int   num = cnt[row];

    float4 acc[NV4];
#pragma unroll
    for (int j = 0; j < NV4; ++j) acc[j] = make_float4(0.f, 0.f, 0.f, 0.f);

    int e = 0;
    for (; e + 4 <= num; e += 4) {
        const int s0 = col[beg + e + 0];
        const int s1 = col[beg + e + 1];
        const int s2 = col[beg + e + 2];
        const int s3 = col[beg + e + 3];
        const float w0 = dinv[s0], w1 = dinv[s1], w2 = dinv[s2], w3 = dinv[s3];
        const float4* p0 = (const float4*)(Lin + (size_t)s0 * D) + lane;
        const float4* p1 = (const float4*)(Lin + (size_t)s1 * D) + lane;
        const float4* p2 = (const float4*)(Lin + (size_t)s2 * D) + lane;
        const float4* p3 = (const float4*)(Lin + (size_t)s3 * D) + lane;
        float4 v0[NV4], v1[NV4], v2[NV4], v3[NV4];
#pragma unroll
        for (int j = 0; j < NV4; ++j) { v0[j] = p0[j * 64]; v1[j] = p1[j * 64];
                                        v2[j] = p2[j * 64]; v3[j] = p3[j * 64]; }
#pragma unroll
        for (int j = 0; j < NV4; ++j) {
            acc[j].x += w0 * v0[j].x + w1 * v1[j].x + w2 * v2[j].x + w3 * v3[j].x;
            acc[j].y += w0 * v0[j].y + w1 * v1[j].y + w2 * v2[j].y + w3 * v3[j].y;
            acc[j].z += w0 * v0[j].z + w1 * v1[j].z + w2 * v2[j].z + w3 * v3[j].z;
            acc[j].w += w0 * v0[j].w + w1 * v1[j].w + w2 * v2[j].w + w3 * v3[j].w;
        }
    }
    for (; e < num; ++e) {
        const int   s = col[beg + e];
        const float w = dinv[s];
        const float4* p = (const float4*)(Lin + (size_t)s * D) + lane;
#pragma unroll
        for (int j = 0; j < NV4; ++j) {
            float4 v = p[j * 64];
            acc[j].x += w * v.x; acc[j].y += w * v.y;
            acc[j].z += w * v.z; acc[j].w += w * v.w;
        }
    }

    const float4* ps = (const float4*)(Lin + (size_t)row * D) + lane;
    const float dr2 = dr * dr;

    if (MODE == 1) {
#pragma unroll
        for (int j = 0; j < NV4; ++j) {
            float4 v = ps[j * 64];
            const float4 b = ((const float4*)bias)[j * 64 + lane];
            float4 o;
            o.x = fmaxf(acc[j].x * dr + dr2 * v.x + b.x, 0.f);
            o.y = fmaxf(acc[j].y * dr + dr2 * v.y + b.y, 0.f);
            o.z = fmaxf(acc[j].z * dr + dr2 * v.z + b.z, 0.f);
            o.w = fmaxf(acc[j].w * dr + dr2 * v.w + b.w, 0.f);
            bf16x4 h, l;
            h[0] = (bf16_t)o.x; l[0] = (bf16_t)(o.x - (float)h[0]);
            h[1] = (bf16_t)o.y; l[1] = (bf16_t)(o.y - (float)h[1]);
            h[2] = (bf16_t)o.z; l[2] = (bf16_t)(o.z - (float)h[2]);
            h[3] = (bf16_t)o.w; l[3] = (bf16_t)(o.w - (float)h[3]);
            const size_t eo = (size_t)row * D + lane * 4 + j * 256;
            *(bf16x4*)(OutH + eo) = h;
            *(bf16x4*)(OutL + eo) = l;
        }
    } else {
        // layer 4: logits -> softmax, all in registers (NV4 == 1, D == 256)
        float4 v = ps[0];
        const float4 b = ((const float4*)bias)[lane];
        float4 o;
        o.x = acc[0].x * dr + dr2 * v.x + b.x;
        o.y = acc[0].y * dr + dr2 * v.y + b.y;
        o.z = acc[0].z * dr + dr2 * v.z + b.z;
        o.w = acc[0].w * dr + dr2 * v.w + b.w;
        float mx = fmaxf(fmaxf(o.x, o.y), fmaxf(o.z, o.w));
#pragma unroll
        for (int off = 32; off > 0; off >>= 1) mx = fmaxf(mx, __shfl_xor(mx, off));
        float e0 = expf(o.x - mx), e1 = expf(o.y - mx),
              e2 = expf(o.z - mx), e3 = expf(o.w - mx);
        float s = e0 + e1 + e2 + e3;
#pragma unroll
        for (int off = 32; off > 0; off >>= 1) s += __shfl_xor(s, off);
        const float inv = 1.0f / s;
        ((float4*)(OutF + (size_t)row * D))[lane] =
            make_float4(e0 * inv, e1 * inv, e2 * inv, e3 * inv);
    }
}

// ------------------------------- launcher ----------------------------------

extern "C" void kernel_launch(void* const* d_in, const int* in_sizes, int n_in,
                              void* d_out, int out_size, void* d_ws, size_t ws_size,
                              hipStream_t stream)
{
    const float* x    = (const float*)d_in[0];
    const int*   eidx = (const int*)d_in[1];      // int32 [2][E]
    const float* W1 = (const float*)d_in[2]; const float* b1 = (const float*)d_in[3];
    const float* W2 = (const float*)d_in[4]; const float* b2 = (const float*)d_in[5];
    const float* W3 = (const float*)d_in[6]; const float* b3 = (const float*)d_in[7];
    const float* W4 = (const float*)d_in[8]; const float* b4 = (const float*)d_in[9];

    const int M = in_sizes[0] / 512;     // 20000
    const int E = in_sizes[1] / 2;       // 320000
    const int DH = 512, DO = 256;

    const int* srcI = eidx;
    const int* dstI = eidx + E;

    // ---- workspace layout (bytes) ----
    char* ws = (char*)d_ws;
    int*    cnt     = (int*)   (ws + 0);
    int*    row_ptr = (int*)   (ws + (1 << 17));
    int*    cursor  = (int*)   (ws + (2 << 17));
    float*  dinv    = (float*) (ws + (3 << 17));
    int*    col     = (int*)   (ws + (4 << 17));          // 1.28MB
    bf16_t* W1h = (bf16_t*)(ws + 2097152);
    bf16_t* W1l = (bf16_t*)(ws + 2621440);
    bf16_t* W2h = (bf16_t*)(ws + 3145728);
    bf16_t* W2l = (bf16_t*)(ws + 3670016);
    bf16_t* W3h = (bf16_t*)(ws + 4194304);
    bf16_t* W3l = (bf16_t*)(ws + 4718592);
    bf16_t* W4h = (bf16_t*)(ws + 5242880);
    bf16_t* W4l = (bf16_t*)(ws + 5505024);
    const size_t HALF = (size_t)20000 * 512 * 2;          // 20.48MB
    bf16_t* PH  = (bf16_t*)(ws + 6291456);                // activation pair (hi)
    bf16_t* PL  = (bf16_t*)(ws + 6291456 + HALF);         // activation pair (lo)
    float*  Lin = (float*) (ws + 6291456 + 2 * HALF);     // f32 GEMM out, 41MB
    float*  out = (float*)d_out;

    const int gN = (M + THREADS - 1) / THREADS;
    const int gE = (E + THREADS - 1) / THREADS;
    const dim3 gemmH((M + 127) / 128, DH / 128);
    const dim3 gemmO((M + 127) / 128, DO / 128);
    const int gAgg = (M + 3) / 4;

    // ---- CSR build ----
    k_zero_int<<<gN, THREADS, 0, stream>>>(cnt, M);
    k_count   <<<gE, THREADS, 0, stream>>>(dstI, cnt, E, M);
    k_dinv    <<<gN, THREADS, 0, stream>>>(cnt, dinv, M);
    k_scan    <<<1, 1024, 0, stream>>>(cnt, row_ptr, cursor, M);
    k_fill    <<<gE, THREADS, 0, stream>>>(srcI, dstI, cursor, col, E, M);

    // ---- operand splits ----
    k_split<<<2048, THREADS, 0, stream>>>(x,  PH,  PL,  M * DH / 4);
    k_split<<<256,  THREADS, 0, stream>>>(W1, W1h, W1l, DH * DH / 4);
    k_split<<<256,  THREADS, 0, stream>>>(W2, W2h, W2l, DH * DH / 4);
    k_split<<<256,  THREADS, 0, stream>>>(W3, W3h, W3l, DH * DH / 4);
    k_split<<<128,  THREADS, 0, stream>>>(W4, W4h, W4l, DO * DH / 4);

    // ---- Layer 1 ----
    k_mfma<<<gemmH, THREADS, 0, stream>>>(PH, PL, W1h, W1l, Lin, M, DH, 512);
    k_agg<2, 1><<<gAgg, THREADS, 0, stream>>>(Lin, nullptr, PH, PL, row_ptr, cnt, col, dinv, b1, M);
    // ---- Layer 2 ----
    k_mfma<<<gemmH, THREADS, 0, stream>>>(PH, PL, W2h, W2l, Lin, M, DH, DH);
    k_agg<2, 1><<<gAgg, THREADS, 0, stream>>>(Lin, nullptr, PH, PL, row_ptr, cnt, col, dinv, b2, M);
    // ---- Layer 3 ----
    k_mfma<<<gemmH, THREADS, 0, stream>>>(PH, PL, W3h, W3l, Lin, M, DH, DH);
    k_agg<2, 1><<<gAgg, THREADS, 0, stream>>>(Lin, nullptr, PH, PL, row_ptr, cnt, col, dinv, b3, M);
    // ---- Layer 4 (fused bias+softmax in agg epilogue) ----
    k_mfma<<<gemmO, THREADS, 0, stream>>>(PH, PL, W4h, W4l, Lin, M, DO, DH);
    k_agg<1, 0><<<gAgg, THREADS, 0, stream>>>(Lin, out, nullptr, nullptr, row_ptr, cnt, col, dinv, b4, M);
}